// Round 10
// baseline (23.859 us; speedup 1.0000x reference)
//
#include <hip/hip_runtime.h>
#include <hip/hip_bf16.h>

typedef __attribute__((ext_vector_type(8))) short short8;
typedef __attribute__((ext_vector_type(4))) float f32x4;

// bf16 truncation (round-toward-zero). Safe: s = ||z3||^2 cancels exactly in
// out = s*d / max(s*sqrt(n1*n2), eps); only d,n1,n2 (pure f32) reach out.
__device__ __forceinline__ unsigned int bfhi(float f) {
    return __builtin_bit_cast(unsigned int, f);
}
__device__ __forceinline__ unsigned int pack2(float lo, float hi) {
    return (bfhi(lo) >> 16) | (bfhi(hi) & 0xffff0000u);
}
__device__ __forceinline__ short8 pack_bf8(float4 a, float4 b) {
    uint4 u;
    u.x = pack2(a.x, a.y);
    u.y = pack2(a.z, a.w);
    u.z = pack2(b.x, b.y);
    u.w = pack2(b.z, b.w);
    return __builtin_bit_cast(short8, u);
}

// ONE kernel. 256 blocks x 512 threads (8 waves), 16 rows/block.
// Phase A: issue ALL X loads up-front (Xq: 6 float4/thread; Xp: 12 float4/lane,
//          half-wave = one row); pack Xq -> LDS bf16 (XOR-swizzled); reduce
//          Xp -> d,n1,n2 -> LDS.
// Phase B: GEMM1 (M=16,N=128,K=768) all 8 waves, W1 f32 loaded with explicit
//          depth-4 pipeline, packed to bf16 in-register.
// Phase C: GEMM2 (waves 0-3), GEMM3 + s=||z3||^2 (waves 0-1).
// Phase D: tid<16 writes out = s*d / max(s*sqrt(n1*n2), eps).
__global__ __launch_bounds__(512, 4) void fused_all(
    const float* __restrict__ X,
    const float* __restrict__ W1, const float* __restrict__ b1,
    const float* __restrict__ W2, const float* __restrict__ b2,
    const float* __restrict__ W3, const float* __restrict__ b3,
    float* __restrict__ out)
{
    __shared__ __align__(16) char xq[16 * 1536];          // 16x768 bf16, XOR-swizzled
    __shared__ __align__(16) unsigned short z1[16][136];
    __shared__ __align__(16) unsigned short z2[16][72];
    __shared__ float sred[2][16];
    __shared__ float d_l[16], n1_l[16], n2_l[16];

    const int tid  = threadIdx.x;
    const int wid  = tid >> 6;
    const int lane = tid & 63;
    const int l15  = lane & 15;
    const int l4   = lane >> 4;
    const int row0 = (int)blockIdx.x * 16;

    // ---------------- Phase A: all X loads up-front ----------------
    {
        // Xq: 1536 16B-chunks / 512 threads = 3 chunks each (8 floats/chunk)
        float4 q[6];
        int qr[3], qc[3];
#pragma unroll
        for (int j = 0; j < 3; ++j) {
            int ci = tid + 512 * j;
            int r  = ci / 96;
            int cc = ci - r * 96;
            qr[j] = r; qc[j] = cc;
            const float* p = X + (size_t)(row0 + r) * 2304 + cc * 8;
            q[2 * j]     = *(const float4*)(p);
            q[2 * j + 1] = *(const float4*)(p + 4);
        }
        // Xp: wave w rows 2w,2w+1; half-wave hl owns one row; 6 float4 per side
        const int hl = lane >> 5, ln = lane & 31;
        const int prow = 2 * wid + hl;
        const float* pb = X + (size_t)(row0 + prow) * 2304;
        float4 p1[6], p2[6];
#pragma unroll
        for (int m = 0; m < 6; ++m) p1[m] = *(const float4*)(pb + 768 + (ln + 32 * m) * 4);
#pragma unroll
        for (int m = 0; m < 6; ++m) p2[m] = *(const float4*)(pb + 1536 + (ln + 32 * m) * 4);

        // pack Xq -> LDS (waits only on q loads)
#pragma unroll
        for (int j = 0; j < 3; ++j) {
            uint4 u;
            u.x = pack2(q[2 * j].x,     q[2 * j].y);
            u.y = pack2(q[2 * j].z,     q[2 * j].w);
            u.z = pack2(q[2 * j + 1].x, q[2 * j + 1].y);
            u.w = pack2(q[2 * j + 1].z, q[2 * j + 1].w);
            int byteoff = (qr[j] * 1536 + qc[j] * 16) ^ ((qr[j] & 7) << 4);
            *(uint4*)(xq + byteoff) = u;
        }
        // reduce Xp -> d, n1, n2 (half-wave butterfly)
        float dd = 0.f, aa = 0.f, bb = 0.f;
#pragma unroll
        for (int m = 0; m < 6; ++m) {
            float4 x = p1[m], y = p2[m];
            dd += x.x * y.x + x.y * y.y + x.z * y.z + x.w * y.w;
            aa += x.x * x.x + x.y * x.y + x.z * x.z + x.w * x.w;
            bb += y.x * y.x + y.y * y.y + y.z * y.z + y.w * y.w;
        }
#pragma unroll
        for (int m = 1; m < 32; m <<= 1) {
            dd += __shfl_xor(dd, m);
            aa += __shfl_xor(aa, m);
            bb += __shfl_xor(bb, m);
        }
        if (ln == 0) {
            d_l[prow]  = dd;
            n1_l[prow] = aa;
            n2_l[prow] = bb;
        }
    }
    __syncthreads();

    // ---------------- Phase B: GEMM1 z1 = relu(Xq @ W1^T + b1) ----------------
    // wave w: cols 16w..16w+15; 24 K-steps; W1 f32 with depth-4 prefetch,
    // packed to bf16 in-register.
    {
        f32x4 acc = {0.f, 0.f, 0.f, 0.f};
        const float* bp = W1 + (size_t)(16 * wid + l15) * 768 + l4 * 8;
        const int abase = l15 * 1536;
        const int aswz  = (l15 & 7) << 4;
        float4 wa[4], wb[4];
#pragma unroll
        for (int i = 0; i < 4; ++i) {
            wa[i] = *(const float4*)(bp + i * 32);
            wb[i] = *(const float4*)(bp + i * 32 + 4);
        }
#pragma unroll
        for (int it = 0; it < 24; ++it) {
            const int k0 = it * 32;
            const int slot = it & 3;
            short8 b = pack_bf8(wa[slot], wb[slot]);
            short8 a = *(const short8*)(xq + ((abase + (k0 + l4 * 8) * 2) ^ aswz));
            acc = __builtin_amdgcn_mfma_f32_16x16x32_bf16(a, b, acc, 0, 0, 0);
            if (it < 20) {
                wa[slot] = *(const float4*)(bp + k0 + 128);
                wb[slot] = *(const float4*)(bp + k0 + 128 + 4);
            }
        }
        float bv = b1[16 * wid + l15];
#pragma unroll
        for (int r = 0; r < 4; ++r) {
            float v = fmaxf(acc[r] + bv, 0.f);
            z1[4 * l4 + r][16 * wid + l15] = (unsigned short)(bfhi(v) >> 16);
        }
    }
    __syncthreads();

    // ---------------- Phase C1: GEMM2 z2 = relu(z1 @ W2^T + b2), waves 0-3 ----
    if (wid < 4) {
        f32x4 acc = {0.f, 0.f, 0.f, 0.f};
        const float* bp = W2 + (size_t)(16 * wid + l15) * 128 + l4 * 8;
#pragma unroll
        for (int ks = 0; ks < 4; ++ks) {
            short8 b = pack_bf8(*(const float4*)(bp + ks * 32),
                                *(const float4*)(bp + ks * 32 + 4));
            short8 a = *(const short8*)&z1[l15][ks * 32 + l4 * 8];
            acc = __builtin_amdgcn_mfma_f32_16x16x32_bf16(a, b, acc, 0, 0, 0);
        }
        float bv = b2[16 * wid + l15];
#pragma unroll
        for (int r = 0; r < 4; ++r) {
            float v = fmaxf(acc[r] + bv, 0.f);
            z2[4 * l4 + r][16 * wid + l15] = (unsigned short)(bfhi(v) >> 16);
        }
    }
    __syncthreads();

    // ---------------- Phase C2: GEMM3 + s = ||z3||^2, waves 0-1 ----------------
    if (wid < 2) {
        f32x4 acc = {0.f, 0.f, 0.f, 0.f};
        const float* bp = W3 + (size_t)(16 * wid + l15) * 64 + l4 * 8;
#pragma unroll
        for (int ks = 0; ks < 2; ++ks) {
            short8 b = pack_bf8(*(const float4*)(bp + ks * 32),
                                *(const float4*)(bp + ks * 32 + 4));
            short8 a = *(const short8*)&z2[l15][ks * 32 + l4 * 8];
            acc = __builtin_amdgcn_mfma_f32_16x16x32_bf16(a, b, acc, 0, 0, 0);
        }
        float bv = b3[16 * wid + l15];
        float sv[4];
#pragma unroll
        for (int r = 0; r < 4; ++r) {
            float v = fmaxf(acc[r] + bv, 0.f);
            sv[r] = v * v;
        }
#pragma unroll
        for (int m = 1; m < 16; m <<= 1)
#pragma unroll
            for (int r = 0; r < 4; ++r) sv[r] += __shfl_xor(sv[r], m);
        if (l15 == 0)
#pragma unroll
            for (int r = 0; r < 4; ++r) sred[wid][4 * l4 + r] = sv[r];
    }
    __syncthreads();

    // ---------------- Phase D: combine ----------------
    if (tid < 16) {
        float s   = sred[0][tid] + sred[1][tid];
        float den = fmaxf(s * sqrtf(n1_l[tid] * n2_l[tid]), 1e-8f);
        out[row0 + tid] = (s * d_l[tid]) / den;
    }
}

extern "C" void kernel_launch(void* const* d_in, const int* in_sizes, int n_in,
                              void* d_out, int out_size, void* d_ws, size_t ws_size,
                              hipStream_t stream)
{
    (void)in_sizes; (void)n_in; (void)out_size; (void)d_ws; (void)ws_size;
    const float* X  = (const float*)d_in[0];
    const float* W1 = (const float*)d_in[1];
    const float* b1 = (const float*)d_in[2];
    const float* W2 = (const float*)d_in[3];
    const float* b2 = (const float*)d_in[4];
    const float* W3 = (const float*)d_in[5];
    const float* b3 = (const float*)d_in[6];

    fused_all<<<dim3(256), dim3(512), 0, stream>>>(X, W1, b1, W2, b2, W3, b3,
                                                   (float*)d_out);
}